// Round 11
// baseline (1470.881 us; speedup 1.0000x reference)
//
#include <hip/hip_runtime.h>
#include <cstdint>

#define ROTL32(v,n) (((v) << (n)) | ((v) >> (32 - (n))))

// ---- JAX threefry-2x32, host version ----
__host__ __forceinline__ void tf2x32(uint32_t k0, uint32_t k1,
                                     uint32_t x0, uint32_t x1,
                                     uint32_t& o0, uint32_t& o1)
{
  uint32_t k2 = k0 ^ k1 ^ 0x1BD11BDAu;
  x0 += k0; x1 += k1;
#define TF_RND(r) { x0 += x1; x1 = ROTL32(x1, (r)); x1 ^= x0; }
  TF_RND(13) TF_RND(15) TF_RND(26) TF_RND(6)
  x0 += k1; x1 += k2 + 1u;
  TF_RND(17) TF_RND(29) TF_RND(16) TF_RND(24)
  x0 += k2; x1 += k0 + 2u;
  TF_RND(13) TF_RND(15) TF_RND(26) TF_RND(6)
  x0 += k0; x1 += k1 + 3u;
  TF_RND(17) TF_RND(29) TF_RND(16) TF_RND(24)
  x0 += k1; x1 += k2 + 4u;
  TF_RND(13) TF_RND(15) TF_RND(26) TF_RND(6)
  x0 += k2; x1 += k0 + 5u;
#undef TF_RND
  o0 = x0; o1 = x1;
}

// ---- device threefry: rotateleft -> v_alignbit_b32 ----
__device__ __forceinline__ void tf2x32_d(uint32_t k0, uint32_t k1,
                                         uint32_t x0, uint32_t x1,
                                         uint32_t& o0, uint32_t& o1)
{
  uint32_t k2 = k0 ^ k1 ^ 0x1BD11BDAu;
  x0 += k0; x1 += k1;
#define R_(r) { x0 += x1; x1 = __builtin_rotateleft32(x1, (r)); x1 ^= x0; }
  R_(13) R_(15) R_(26) R_(6)
  x0 += k1; x1 += k2 + 1u;
  R_(17) R_(29) R_(16) R_(24)
  x0 += k2; x1 += k0 + 2u;
  R_(13) R_(15) R_(26) R_(6)
  x0 += k0; x1 += k1 + 3u;
  R_(17) R_(29) R_(16) R_(24)
  x0 += k1; x1 += k2 + 4u;
  R_(13) R_(15) R_(26) R_(6)
  x0 += k2; x1 += k0 + 5u;
#undef R_
  o0 = x0; o1 = x1;
}

typedef __attribute__((ext_vector_type(8))) _Float16 h16x8;
typedef __attribute__((ext_vector_type(4))) float fl32x4;

__device__ __forceinline__ float u2unit_f(uint32_t b) {
  uint32_t r = (b >> 9) | 0x3F800000u;
  float f; __builtin_memcpy(&f, &r, 4); return f - 1.0f;
}

// async global->LDS, 16B per lane; LDS dest = wave-uniform base + lane*16 (m104)
#define GLD16(gp, lp) \
  __builtin_amdgcn_global_load_lds( \
      (__attribute__((address_space(1))) void*)(gp), \
      (__attribute__((address_space(3))) void*)(lp), 16, 0, 0)

#define VMW(n) asm volatile("s_waitcnt vmcnt(" #n ")" ::: "memory")
#define SBAR() asm volatile("s_barrier" ::: "memory")

// ---- x convert + pad (65536,784)f32 -> (65536,832)fp16, + produce L0 masks ----
__global__ __launch_bounds__(256) void cvt_x_f(const float* __restrict__ x,
                                               _Float16* __restrict__ xp,
                                               unsigned long long* __restrict__ m0,
                                               uint32_t k0, uint32_t k1)
{
  int idx = blockIdx.x * 256 + threadIdx.x;   // 65536*104 chunks of 8
  int row = idx / 104, c = idx - row * 104;
  h16x8 o = {0,0,0,0,0,0,0,0};
  if (c < 98) {
    const fl32x4* p = (const fl32x4*)&x[row * 784 + c * 8];
    fl32x4 a = p[0], b = p[1];
    o[0] = (_Float16)a[0]; o[1] = (_Float16)a[1]; o[2] = (_Float16)a[2]; o[3] = (_Float16)a[3];
    o[4] = (_Float16)b[0]; o[5] = (_Float16)b[1]; o[6] = (_Float16)b[2]; o[7] = (_Float16)b[3];
  }
  *(h16x8*)&xp[row * 832 + c * 8] = o;

  // L0 dropout masks (p=0.2): 524288 words over 106496 waves -> 5 words/wave
  uint32_t lane = threadIdx.x & 63u;
  uint32_t gw = (uint32_t)blockIdx.x * 4u + ((uint32_t)threadIdx.x >> 6);
#pragma unroll
  for (int i = 0; i < 5; ++i) {
    uint32_t wix = gw * 5u + (uint32_t)i;
    if (wix < 524288u) {                      // wave-uniform guard
      uint32_t b1, b2;
      tf2x32_d(k0, k1, 0u, wix * 64u + lane, b1, b2);
      unsigned long long mw = __ballot(u2unit_f(b1 ^ b2) < 0.8f);
      if (lane == 0) m0[wix] = mw;
    }
  }
}

// ---- weight transpose+convert: W(K,N) f32 -> WT(N,K) fp16 (W1 padded to K=832) ----
__global__ __launch_bounds__(256) void cvt_w_f(
    const float* __restrict__ W1, const float* __restrict__ W2, const float* __restrict__ W3,
    const float* __restrict__ W4, const float* __restrict__ W5, const float* __restrict__ W6,
    const float* __restrict__ W7, _Float16* __restrict__ WT1, _Float16* __restrict__ WT)
{
  int b = blockIdx.x;
  if (b < 1666) {                              // 512*832 = 426496 elems
    int idx = b * 256 + threadIdx.x;           // n*832 + k
    int n = idx / 832, k = idx - n * 832;
    WT1[idx] = (k < 784) ? (_Float16)W1[k * 512 + n] : (_Float16)0.f;
  } else {                                     // 6 layers of 512*512
    int l = (b - 1666) >> 10;
    int idx = ((b - 1666) & 1023) * 256 + threadIdx.x;
    int n = idx >> 9, k = idx & 511;
    const float* Wp = (l == 0) ? W2 : (l == 1) ? W3 : (l == 2) ? W4
                    : (l == 3) ? W5 : (l == 4) ? W6 : W7;
    WT[l * 262144 + idx] = (_Float16)Wp[k * 512 + n];
  }
}

// ---- GEMM: 256x128 tile, BK=32, 512 thr / 8 waves, 2-slot LDS, vmcnt(3), ----
// ---- LDS-staged COALESCED C-write epilogue (fixes the 2B-scatter write wall) ----
// Wave (wr=wv>>1 in 0..3: 64 rows; wc=wv&1: 64 cols): 4x4 16x16 frags.
// Staging/read swizzle = r9's (measured conflict-free). LDS 48 KB -> 2 blk/CU.
template<bool DROP>
__global__ __launch_bounds__(512, 4) void gemm_c(
    const _Float16* __restrict__ A, const _Float16* __restrict__ BT,
    const float* __restrict__ bias, const unsigned long long* __restrict__ mask,
    float invq, _Float16* __restrict__ C, int K,
    unsigned long long* __restrict__ mout, uint32_t mbase, int tfcap, int tfpp,
    uint32_t mk0, uint32_t mk1, float mq)
{
  __shared__ __align__(16) _Float16 sm[24576];   // 49152 B: 2 slots x (A 8192 + B 4096 elems)
  const int tid  = threadIdx.x;
  const int lane = tid & 63;
  const int wv   = tid >> 6;
  const int wr   = wv >> 1, wc = wv & 1;
  const int rml  = lane & 15;
  const int kq   = lane >> 4;

  // bijective XCD swizzle: 1024 blocks = 8 x 128; consecutive t share the A panel
  int bid = blockIdx.x;
  int t = (bid & 7) * 128 + (bid >> 3);
  int bm = (t >> 2) * 256;
  int bn = (t & 3) * 128;

  const _Float16* Ab = A + (size_t)bm * K;
  const _Float16* Bb = BT + (size_t)bn * K;

  // staging constants (r9, conflict-free): thread -> A chunks {tid,512+tid}, B {tid}
  const int sp   = tid >> 3;
  const int sin  = (tid & 7) ^ (sp & 7);           // inverse swizzle
  const int srow = 2 * sp + (sin >> 2);            // source row (0..127 / 0..255)
  const int sk16 = sin & 3;                        // source k-chunk

  // read constants: slot = ((rml&1)<<2 | kq) ^ (rml>>1)
  const int rslot = (((rml & 1) << 2) | kq) ^ (rml >> 1);
  const int abase = (wr * 32 + (rml >> 1)) * 64 + rslot * 8;
  const int bbase = 8192 + (wc * 32 + (rml >> 1)) * 64 + rslot * 8;

  fl32x4 acc[4][4];
#pragma unroll
  for (int i = 0; i < 4; ++i)
#pragma unroll
    for (int j = 0; j < 4; ++j)
      acc[i][j] = (fl32x4){0.f, 0.f, 0.f, 0.f};

  const int nst = K >> 5;

#define STAGE(slotb, kt) do {                                                  \
    GLD16(Ab + (size_t)srow * K + (kt) * 32 + sk16 * 8,                        \
          sm + (slotb) + wv * 512);                                            \
    GLD16(Ab + (size_t)(srow + 128) * K + (kt) * 32 + sk16 * 8,                \
          sm + (slotb) + 4096 + wv * 512);                                     \
    GLD16(Bb + (size_t)srow * K + (kt) * 32 + sk16 * 8,                        \
          sm + (slotb) + 8192 + wv * 512);                                     \
  } while (0)

  STAGE(0, 0);

  uint64_t mw0 = 0;
  int tfc = 0;
  uint32_t gw = (uint32_t)bid * 8u + (uint32_t)wv;

#pragma unroll 1
  for (int kt = 0; kt < nst; ++kt) {
    const int slot = (kt & 1) * 12288;
    if (kt + 1 < nst) STAGE(12288 - slot, kt + 1);
    // hosted threefry mask words (register-held, stored once after loop)
    if (mout != nullptr) {
      int todo = tfcap - tfc; if (todo > tfpp) todo = tfpp;
      for (int i_ = 0; i_ < todo; ++i_) {
        uint32_t a_, b_;
        tf2x32_d(mk0, mk1, 0u,
                 (mbase + gw * (uint32_t)tfcap + (uint32_t)tfc) * 64u + (uint32_t)lane,
                 a_, b_);
        unsigned long long bal = __ballot(u2unit_f(a_ ^ b_) < mq);
        if (lane == tfc) mw0 = bal;
        ++tfc;
      }
    }
    if (kt + 1 < nst) { VMW(3); } else { VMW(0); }   // counted: own 3 stay in flight
    SBAR();
    h16x8 af[4], bf[4];
#pragma unroll
    for (int mf = 0; mf < 4; ++mf)
      af[mf] = *(const h16x8*)&sm[slot + abase + mf * 512];
#pragma unroll
    for (int nf = 0; nf < 4; ++nf)
      bf[nf] = *(const h16x8*)&sm[slot + bbase + nf * 512];
    __builtin_amdgcn_s_setprio(1);
#pragma unroll
    for (int mf = 0; mf < 4; ++mf)
#pragma unroll
      for (int nf = 0; nf < 4; ++nf)
        acc[mf][nf] = __builtin_amdgcn_mfma_f32_16x16x32_f16(af[mf], bf[nf], acc[mf][nf], 0, 0, 0);
    __builtin_amdgcn_s_setprio(0);
    SBAR();
  }
#undef STAGE

  // mask words: lane i holds word i -> one coalesced store per wave
  if (mout != nullptr && lane < tfcap)
    mout[mbase + gw * (uint32_t)tfcap + (uint32_t)lane] = mw0;

  // ---- epilogue: bias+(drop)+relu in regs -> LDS (swizzled) -> coalesced stores ----
  // Two half-tile passes (rows 0-127 by waves wr<2, rows 128-255 by wr>=2).
  // LDS C layout: [128 rows][128 cols], 16B-chunk swizzle: chunk^(row&7).
#pragma unroll 1
  for (int pass = 0; pass < 2; ++pass) {
    if ((wr >> 1) == pass) {
#pragma unroll
      for (int nf = 0; nf < 4; ++nf) {
        int colloc = wc * 64 + nf * 16 + rml;
        int col = bn + colloc;
        float bv = bias[col];
#pragma unroll
        for (int mf = 0; mf < 4; ++mf) {
#pragma unroll
          for (int r = 0; r < 4; ++r) {
            int lr  = (wr & 1) * 64 + mf * 16 + kq * 4 + r;   // local row 0..127
            int row = bm + pass * 128 + lr;
            float v = acc[mf][nf][r] + bv;
            if (DROP) {
              uint32_t j = (uint32_t)row * 512u + (uint32_t)col;
              unsigned long long mw = mask[j >> 6];
              v = ((mw >> (j & 63)) & 1ull) ? v * invq : 0.0f;
            }
            v = fmaxf(v, 0.0f);
            sm[lr * 128 + ((((colloc >> 3) & 15) ^ (lr & 7)) << 3) + (colloc & 7)] = (_Float16)v;
          }
        }
      }
    }
    __syncthreads();
    // all 512 threads: 32 KB out, 16B/lane, 64B-contiguous runs per 4-lane group
    {
      int rr = tid >> 2, seg = tid & 3;
#pragma unroll
      for (int c4 = 0; c4 < 4; ++c4) {
        int chunk = c4 * 4 + seg;
        h16x8 v = *(const h16x8*)&sm[rr * 128 + ((chunk ^ (rr & 7)) << 3)];
        *(h16x8*)&C[(size_t)(bm + pass * 128 + rr) * 512 + bn + chunk * 8] = v;
      }
    }
    __syncthreads();
  }
}

// ---- head: logits = h@W8 + b8 (512->10), softmax, fp32 out ----
__global__ __launch_bounds__(256) void head_f(
    const _Float16* __restrict__ H, const float* __restrict__ W8,
    const float* __restrict__ b8, float* __restrict__ out)
{
  __shared__ float Wl[5120];                   // 512x10 fp32
  for (int i = threadIdx.x; i < 5120; i += 256) Wl[i] = W8[i];
  __syncthreads();
  int lane = threadIdx.x & 63;
  int wv = threadIdx.x >> 6;
  int row = blockIdx.x * 4 + wv;               // one row per wave
  h16x8 h = *(const h16x8*)&H[(size_t)row * 512 + lane * 8];
  float acc[10];
#pragma unroll
  for (int n = 0; n < 10; ++n) acc[n] = 0.f;
#pragma unroll
  for (int j = 0; j < 8; ++j) {
    float hf = (float)h[j];
    const float* wrow = &Wl[(lane * 8 + j) * 10];
#pragma unroll
    for (int n = 0; n < 10; ++n) acc[n] += hf * wrow[n];
  }
#pragma unroll
  for (int off = 1; off < 64; off <<= 1) {
#pragma unroll
    for (int n = 0; n < 10; ++n) acc[n] += __shfl_xor(acc[n], off);
  }
  if (lane == 0) {
    float mx = -3.0e38f;
#pragma unroll
    for (int n = 0; n < 10; ++n) { acc[n] += b8[n]; mx = fmaxf(mx, acc[n]); }
    float s = 0.f, e[10];
#pragma unroll
    for (int n = 0; n < 10; ++n) { e[n] = expf(acc[n] - mx); s += e[n]; }
    float is = 1.0f / s;
#pragma unroll
    for (int n = 0; n < 10; ++n) out[(size_t)row * 10 + n] = e[n] * is;
  }
}

extern "C" void kernel_launch(void* const* d_in, const int* in_sizes, int n_in,
                              void* d_out, int out_size, void* d_ws, size_t ws_size,
                              hipStream_t stream) {
  (void)in_sizes; (void)n_in; (void)out_size; (void)ws_size;
  const float* x = (const float*)d_in[0];
  const float* W[8]; const float* B[8];
  for (int i = 0; i < 8; ++i) { W[i] = (const float*)d_in[1 + 2*i]; B[i] = (const float*)d_in[2 + 2*i]; }

  char* w = (char*)d_ws;                       // ~260 MB total
  _Float16* xpad = (_Float16*)(w);             // 65536*832 fp16   = 109,051,904 B
  _Float16* hA   = (_Float16*)(w + 109051904); // 65536*512 fp16   =  67,108,864 B
  _Float16* hB   = (_Float16*)(w + 176160768); // 65536*512 fp16   =  67,108,864 B
  _Float16* WT1  = (_Float16*)(w + 243269632); // 512*832 fp16     =     851,968 B
  _Float16* WT   = (_Float16*)(w + 244121600); // 6 x 512*512 fp16 =   3,145,728 B
  unsigned long long* masks = (unsigned long long*)(w + 247267328); // 3*4 MiB
  unsigned long long* mL0 = masks;
  unsigned long long* mL1 = masks + 524288;
  unsigned long long* mL2 = masks + 1048576;

  // jax.random.split(key(42), 3), threefry_partitionable (foldlike) path:
  // child i = BOTH output words of threefry(key=(0,42), counter=(0,i))
  uint32_t d00,d01,d10,d11,d20,d21;
  tf2x32(0u, 42u, 0u, 0u, d00, d01);           // dk[0]  (p=0.2, q=0.8)
  tf2x32(0u, 42u, 0u, 1u, d10, d11);           // dk[1]  (p=0.3, q=0.7)
  tf2x32(0u, 42u, 0u, 2u, d20, d21);           // dk[2]  (p=0.5, q=0.5)

  cvt_x_f<<<26624, 256, 0, stream>>>(x, xpad, mL0, d00, d01);
  cvt_w_f<<<7810, 256, 0, stream>>>(W[0],W[1],W[2],W[3],W[4],W[5],W[6], WT1, WT);

  dim3 g(1024), b(512);
  // masks: mL0 by cvt_x (used g2); mL1 by g1 (used g4); mL2 by g2+g3 (used g6)
  // coverage: 1024 blk x 8 waves = 8192 waves; 8192*64 = 524288, 8192*32 = 262144
  gemm_c<false><<<g, b, 0, stream>>>(xpad, WT1,           B[0], nullptr, 1.0f,      hA, 832,
                                     mL1, 0u,       64, 3, d10, d11, 0.7f);
  gemm_c<true ><<<g, b, 0, stream>>>(hA,   WT + 0*262144, B[1], mL0,     1.0f/0.8f, hB, 512,
                                     mL2, 0u,       32, 2, d20, d21, 0.5f);
  gemm_c<false><<<g, b, 0, stream>>>(hB,   WT + 1*262144, B[2], nullptr, 1.0f,      hA, 512,
                                     mL2, 262144u,  32, 2, d20, d21, 0.5f);
  gemm_c<true ><<<g, b, 0, stream>>>(hA,   WT + 2*262144, B[3], mL1,     1.0f/0.7f, hB, 512,
                                     nullptr, 0u, 0, 0, 0u, 0u, 0.f);
  gemm_c<false><<<g, b, 0, stream>>>(hB,   WT + 3*262144, B[4], nullptr, 1.0f,      hA, 512,
                                     nullptr, 0u, 0, 0, 0u, 0u, 0.f);
  gemm_c<true ><<<g, b, 0, stream>>>(hA,   WT + 4*262144, B[5], mL2,     2.0f,      hB, 512,
                                     nullptr, 0u, 0, 0, 0u, 0u, 0.f);
  gemm_c<false><<<g, b, 0, stream>>>(hB,   WT + 5*262144, B[6], nullptr, 1.0f,      hA, 512,
                                     nullptr, 0u, 0, 0, 0u, 0u, 0.f);
  head_f<<<16384, 256, 0, stream>>>(hA, W[7], B[7], (float*)d_out);
}

// Round 13
// 690.289 us; speedup vs baseline: 2.1308x; 2.1308x over previous
//
#include <hip/hip_runtime.h>
#include <cstdint>

#define ROTL32(v,n) (((v) << (n)) | ((v) >> (32 - (n))))

// ---- JAX threefry-2x32, host version ----
__host__ __forceinline__ void tf2x32(uint32_t k0, uint32_t k1,
                                     uint32_t x0, uint32_t x1,
                                     uint32_t& o0, uint32_t& o1)
{
  uint32_t k2 = k0 ^ k1 ^ 0x1BD11BDAu;
  x0 += k0; x1 += k1;
#define TF_RND(r) { x0 += x1; x1 = ROTL32(x1, (r)); x1 ^= x0; }
  TF_RND(13) TF_RND(15) TF_RND(26) TF_RND(6)
  x0 += k1; x1 += k2 + 1u;
  TF_RND(17) TF_RND(29) TF_RND(16) TF_RND(24)
  x0 += k2; x1 += k0 + 2u;
  TF_RND(13) TF_RND(15) TF_RND(26) TF_RND(6)
  x0 += k0; x1 += k1 + 3u;
  TF_RND(17) TF_RND(29) TF_RND(16) TF_RND(24)
  x0 += k1; x1 += k2 + 4u;
  TF_RND(13) TF_RND(15) TF_RND(26) TF_RND(6)
  x0 += k2; x1 += k0 + 5u;
#undef TF_RND
  o0 = x0; o1 = x1;
}

// ---- device threefry: rotateleft -> v_alignbit_b32 ----
__device__ __forceinline__ void tf2x32_d(uint32_t k0, uint32_t k1,
                                         uint32_t x0, uint32_t x1,
                                         uint32_t& o0, uint32_t& o1)
{
  uint32_t k2 = k0 ^ k1 ^ 0x1BD11BDAu;
  x0 += k0; x1 += k1;
#define R_(r) { x0 += x1; x1 = __builtin_rotateleft32(x1, (r)); x1 ^= x0; }
  R_(13) R_(15) R_(26) R_(6)
  x0 += k1; x1 += k2 + 1u;
  R_(17) R_(29) R_(16) R_(24)
  x0 += k2; x1 += k0 + 2u;
  R_(13) R_(15) R_(26) R_(6)
  x0 += k0; x1 += k1 + 3u;
  R_(17) R_(29) R_(16) R_(24)
  x0 += k1; x1 += k2 + 4u;
  R_(13) R_(15) R_(26) R_(6)
  x0 += k2; x1 += k0 + 5u;
#undef R_
  o0 = x0; o1 = x1;
}

typedef __attribute__((ext_vector_type(8))) _Float16 h16x8;
typedef __attribute__((ext_vector_type(4))) float fl32x4;
typedef __attribute__((ext_vector_type(2))) unsigned long long u64x2;

__device__ __forceinline__ float u2unit_f(uint32_t b) {
  uint32_t r = (b >> 9) | 0x3F800000u;
  float f; __builtin_memcpy(&f, &r, 4); return f - 1.0f;
}

// async global->LDS, 16B per lane; LDS dest = wave-uniform base + lane*16 (m104)
#define GLD16(gp, lp) \
  __builtin_amdgcn_global_load_lds( \
      (__attribute__((address_space(1))) void*)(gp), \
      (__attribute__((address_space(3))) void*)(lp), 16, 0, 0)

#define VMW(n) asm volatile("s_waitcnt vmcnt(" #n ")" ::: "memory")
#define LKW0() asm volatile("s_waitcnt lgkmcnt(0)" ::: "memory")
#define SBAR() asm volatile("s_barrier" ::: "memory")

// ---- x convert + pad (65536,784)f32 -> (65536,832)fp16, + produce L0 masks ----
// Masks: LINEAR word layout (r4-r11 passing form): word wix covers elems [wix*64,+64)
__global__ __launch_bounds__(256) void cvt_x_f(const float* __restrict__ x,
                                               _Float16* __restrict__ xp,
                                               unsigned long long* __restrict__ m0,
                                               uint32_t k0, uint32_t k1)
{
  int idx = blockIdx.x * 256 + threadIdx.x;   // 65536*104 chunks of 8
  int row = idx / 104, c = idx - row * 104;
  h16x8 o = {0,0,0,0,0,0,0,0};
  if (c < 98) {
    const fl32x4* p = (const fl32x4*)&x[row * 784 + c * 8];
    fl32x4 a = p[0], b = p[1];
    o[0] = (_Float16)a[0]; o[1] = (_Float16)a[1]; o[2] = (_Float16)a[2]; o[3] = (_Float16)a[3];
    o[4] = (_Float16)b[0]; o[5] = (_Float16)b[1]; o[6] = (_Float16)b[2]; o[7] = (_Float16)b[3];
  }
  *(h16x8*)&xp[row * 832 + c * 8] = o;

  // L0 dropout masks (p=0.2): 524288 words over 106496 waves -> 5 words/wave
  uint32_t lane = threadIdx.x & 63u;
  uint32_t gw = (uint32_t)blockIdx.x * 4u + ((uint32_t)threadIdx.x >> 6);
#pragma unroll
  for (int i = 0; i < 5; ++i) {
    uint32_t wix = gw * 5u + (uint32_t)i;
    if (wix < 524288u) {                      // wave-uniform guard
      uint32_t b1, b2;
      tf2x32_d(k0, k1, 0u, wix * 64u + lane, b1, b2);
      unsigned long long mw = __ballot(u2unit_f(b1 ^ b2) < 0.8f);
      if (lane == 0) m0[wix] = mw;
    }
  }
}

// ---- weight transpose+convert: W(K,N) f32 -> WT(N,K) fp16 (W1 padded to K=832) ----
__global__ __launch_bounds__(256) void cvt_w_f(
    const float* __restrict__ W1, const float* __restrict__ W2, const float* __restrict__ W3,
    const float* __restrict__ W4, const float* __restrict__ W5, const float* __restrict__ W6,
    const float* __restrict__ W7, _Float16* __restrict__ WT1, _Float16* __restrict__ WT)
{
  int b = blockIdx.x;
  if (b < 1666) {                              // 512*832 = 426496 elems
    int idx = b * 256 + threadIdx.x;           // n*832 + k
    int n = idx / 832, k = idx - n * 832;
    WT1[idx] = (k < 784) ? (_Float16)W1[k * 512 + n] : (_Float16)0.f;
  } else {                                     // 6 layers of 512*512
    int l = (b - 1666) >> 10;
    int idx = ((b - 1666) & 1023) * 256 + threadIdx.x;
    int n = idx >> 9, k = idx & 511;
    const float* Wp = (l == 0) ? W2 : (l == 1) ? W3 : (l == 2) ? W4
                    : (l == 3) ? W5 : (l == 4) ? W6 : W7;
    WT[l * 262144 + idx] = (_Float16)Wp[k * 512 + n];
  }
}

// ---- GEMM: 256x128 tile, BK=32, 512 thr / 8 waves, r9's proven 2-slot/2-barrier ----
// k-loop + register-held mask hosting (r11) + per-wave coalesced flush epilogue.
// Wave (wr=wv>>1, wc=wv&1): 64x64 out = 4x4 16x16 frags.
// Epilogue: wave-private LDS region (64 rows x stride 68), lane flushes one row
// = 128B contiguous store; dropout applied at flush as exact zeroing with ONE
// linear mask word per lane: word = grow*8 + cb, bit = col&63.
template<bool DROP>
__global__ __launch_bounds__(512, 4) void gemm_r(
    const _Float16* __restrict__ A, const _Float16* __restrict__ BT,
    const float* __restrict__ bias, const unsigned long long* __restrict__ mask,
    float invq, _Float16* __restrict__ C, int K,
    unsigned long long* __restrict__ mout, uint32_t mbase, int tfcap, int tfpp,
    uint32_t mk0, uint32_t mk1, float mq)
{
  __shared__ __align__(16) _Float16 sm[34816];   // 69632 B: 2 k-slots (24576) / epi (34816)
  const int tid  = threadIdx.x;
  const int lane = tid & 63;
  const int wv   = tid >> 6;
  const int wr   = wv >> 1, wc = wv & 1;
  const int rml  = lane & 15;
  const int kq   = lane >> 4;

  // bijective XCD swizzle: 1024 blocks = 8 x 128; consecutive t share the A panel
  int bid = blockIdx.x;
  int t = (bid & 7) * 128 + (bid >> 3);
  int bm = (t >> 2) * 256;
  int bn = (t & 3) * 128;

  const _Float16* Ab = A + (size_t)bm * K;
  const _Float16* Bb = BT + (size_t)bn * K;

  // staging constants (r9, conflict-free)
  const int sp   = tid >> 3;
  const int sin  = (tid & 7) ^ (sp & 7);
  const int srow = 2 * sp + (sin >> 2);
  const int sk16 = sin & 3;

  // read constants (r9): slot16 = ((rml&1)<<2 | kq) ^ (rml>>1)
  const int rslot = (((rml & 1) << 2) | kq) ^ (rml >> 1);
  const int abase = (wr * 32 + (rml >> 1)) * 64 + rslot * 8;
  const int bbase = 8192 + (wc * 32 + (rml >> 1)) * 64 + rslot * 8;

  fl32x4 acc[4][4];
#pragma unroll
  for (int i = 0; i < 4; ++i)
#pragma unroll
    for (int j = 0; j < 4; ++j)
      acc[i][j] = (fl32x4){0.f, 0.f, 0.f, 0.f};

  const int nst = K >> 5;

#define STAGE(selem, kt) do {                                                  \
    GLD16(Ab + (size_t)srow * K + (kt) * 32 + sk16 * 8,                        \
          sm + (selem) + wv * 512);                                            \
    GLD16(Ab + (size_t)(srow + 128) * K + (kt) * 32 + sk16 * 8,                \
          sm + (selem) + 4096 + wv * 512);                                     \
    GLD16(Bb + (size_t)srow * K + (kt) * 32 + sk16 * 8,                        \
          sm + (selem) + 8192 + wv * 512);                                     \
  } while (0)

  STAGE(0, 0);

  uint64_t mw0 = 0;
  int tfc = 0;
  uint32_t gw = (uint32_t)bid * 8u + (uint32_t)wv;

#pragma unroll 1
  for (int kt = 0; kt < nst; ++kt) {
    const int slot = (kt & 1) * 12288;
    if (kt + 1 < nst) STAGE(12288 - slot, kt + 1);
    // hosted threefry mask words (register-held; no in-loop memory ops)
    if (mout != nullptr) {
      int todo = tfcap - tfc; if (todo > tfpp) todo = tfpp;
      for (int i_ = 0; i_ < todo; ++i_) {
        uint32_t a_, b_;
        tf2x32_d(mk0, mk1, 0u,
                 (mbase + gw * (uint32_t)tfcap + (uint32_t)tfc) * 64u + (uint32_t)lane,
                 a_, b_);
        unsigned long long bal = __ballot(u2unit_f(a_ ^ b_) < mq);
        if (lane == tfc) mw0 = bal;
        ++tfc;
      }
    }
    if (kt + 1 < nst) { VMW(3); } else { VMW(0); }   // counted: own 3 stay in flight
    SBAR();
    h16x8 af[4], bf[4];
#pragma unroll
    for (int mf = 0; mf < 4; ++mf)
      af[mf] = *(const h16x8*)&sm[slot + abase + mf * 512];
#pragma unroll
    for (int nf = 0; nf < 4; ++nf)
      bf[nf] = *(const h16x8*)&sm[slot + bbase + nf * 512];
    __builtin_amdgcn_s_setprio(1);
#pragma unroll
    for (int mf = 0; mf < 4; ++mf)
#pragma unroll
      for (int nf = 0; nf < 4; ++nf)
        acc[mf][nf] = __builtin_amdgcn_mfma_f32_16x16x32_f16(af[mf], bf[nf], acc[mf][nf], 0, 0, 0);
    __builtin_amdgcn_s_setprio(0);
    SBAR();                                    // guards 2-slot reuse next step
  }
#undef STAGE

  // mask words out (LINEAR layout), one coalesced store per wave
  if (mout != nullptr && lane < tfcap)
    mout[mbase + gw * (uint32_t)tfcap + (uint32_t)lane] = mw0;

  // ---- per-wave epilogue: regs -> LDS (stride-68 rows) -> 128B/lane stores ----
  const int eb = wv * 4352;                    // 64 rows x 68 elems per wave
#pragma unroll
  for (int nf = 0; nf < 4; ++nf) {
    int colq = nf * 16 + rml;
    float bv = bias[bn + wc * 64 + colq];
#pragma unroll
    for (int mf = 0; mf < 4; ++mf) {
#pragma unroll
      for (int r = 0; r < 4; ++r) {
        int lr = mf * 16 + kq * 4 + r;
        float v = fmaxf(acc[mf][nf][r] + bv, 0.0f) * invq;
        sm[eb + lr * 68 + colq] = (_Float16)v;
      }
    }
  }
  LKW0();                                      // wave's LDS writes visible to its reads
  // flush: lane owns row `lane` of the wave's 64x64 quadrant
  {
    int grow = bm + wr * 64 + lane;
    int col0 = bn + wc * 64;
    uint64_t mw = 0;
    if (DROP) mw = mask[(size_t)grow * 8 + (size_t)(col0 >> 6)];  // linear word
#pragma unroll
    for (int c = 0; c < 8; ++c) {
      uint64_t lo = *(const uint64_t*)&sm[eb + lane * 68 + c * 8];
      uint64_t hi = *(const uint64_t*)&sm[eb + lane * 68 + c * 8 + 4];
      if (DROP) {
        uint32_t bits = (uint32_t)(mw >> (c * 8)) & 0xffu;
        uint64_t klo = 0, khi = 0;
        if (bits & 0x01u) klo |= 0x000000000000ffffull;
        if (bits & 0x02u) klo |= 0x00000000ffff0000ull;
        if (bits & 0x04u) klo |= 0x0000ffff00000000ull;
        if (bits & 0x08u) klo |= 0xffff000000000000ull;
        if (bits & 0x10u) khi |= 0x000000000000ffffull;
        if (bits & 0x20u) khi |= 0x00000000ffff0000ull;
        if (bits & 0x40u) khi |= 0x0000ffff00000000ull;
        if (bits & 0x80u) khi |= 0xffff000000000000ull;
        lo &= klo; hi &= khi;
      }
      u64x2 ov; ov[0] = lo; ov[1] = hi;
      *(u64x2*)&C[(size_t)grow * 512 + col0 + c * 8] = ov;
    }
  }
}

// ---- head: logits = h@W8 + b8 (512->10), softmax, fp32 out ----
__global__ __launch_bounds__(256) void head_f(
    const _Float16* __restrict__ H, const float* __restrict__ W8,
    const float* __restrict__ b8, float* __restrict__ out)
{
  __shared__ float Wl[5120];                   // 512x10 fp32
  for (int i = threadIdx.x; i < 5120; i += 256) Wl[i] = W8[i];
  __syncthreads();
  int lane = threadIdx.x & 63;
  int wv = threadIdx.x >> 6;
  int row = blockIdx.x * 4 + wv;               // one row per wave
  h16x8 h = *(const h16x8*)&H[(size_t)row * 512 + lane * 8];
  float acc[10];
#pragma unroll
  for (int n = 0; n < 10; ++n) acc[n] = 0.f;
#pragma unroll
  for (int j = 0; j < 8; ++j) {
    float hf = (float)h[j];
    const float* wrow = &Wl[(lane * 8 + j) * 10];
#pragma unroll
    for (int n = 0; n < 10; ++n) acc[n] += hf * wrow[n];
  }
#pragma unroll
  for (int off = 1; off < 64; off <<= 1) {
#pragma unroll
    for (int n = 0; n < 10; ++n) acc[n] += __shfl_xor(acc[n], off);
  }
  if (lane == 0) {
    float mx = -3.0e38f;
#pragma unroll
    for (int n = 0; n < 10; ++n) { acc[n] += b8[n]; mx = fmaxf(mx, acc[n]); }
    float s = 0.f, e[10];
#pragma unroll
    for (int n = 0; n < 10; ++n) { e[n] = expf(acc[n] - mx); s += e[n]; }
    float is = 1.0f / s;
#pragma unroll
    for (int n = 0; n < 10; ++n) out[(size_t)row * 10 + n] = e[n] * is;
  }
}

extern "C" void kernel_launch(void* const* d_in, const int* in_sizes, int n_in,
                              void* d_out, int out_size, void* d_ws, size_t ws_size,
                              hipStream_t stream) {
  (void)in_sizes; (void)n_in; (void)out_size; (void)ws_size;
  const float* x = (const float*)d_in[0];
  const float* W[8]; const float* B[8];
  for (int i = 0; i < 8; ++i) { W[i] = (const float*)d_in[1 + 2*i]; B[i] = (const float*)d_in[2 + 2*i]; }

  char* w = (char*)d_ws;                       // ~260 MB total
  _Float16* xpad = (_Float16*)(w);             // 65536*832 fp16   = 109,051,904 B
  _Float16* hA   = (_Float16*)(w + 109051904); // 65536*512 fp16   =  67,108,864 B
  _Float16* hB   = (_Float16*)(w + 176160768); // 65536*512 fp16   =  67,108,864 B
  _Float16* WT1  = (_Float16*)(w + 243269632); // 512*832 fp16     =     851,968 B
  _Float16* WT   = (_Float16*)(w + 244121600); // 6 x 512*512 fp16 =   3,145,728 B
  unsigned long long* masks = (unsigned long long*)(w + 247267328); // 3*4 MiB
  unsigned long long* mL0 = masks;
  unsigned long long* mL1 = masks + 524288;
  unsigned long long* mL2 = masks + 1048576;

  // jax.random.split(key(42), 3), threefry_partitionable (foldlike) path:
  // child i = BOTH output words of threefry(key=(0,42), counter=(0,i))
  uint32_t d00,d01,d10,d11,d20,d21;
  tf2x32(0u, 42u, 0u, 0u, d00, d01);           // dk[0]  (p=0.2, q=0.8)
  tf2x32(0u, 42u, 0u, 1u, d10, d11);           // dk[1]  (p=0.3, q=0.7)
  tf2x32(0u, 42u, 0u, 2u, d20, d21);           // dk[2]  (p=0.5, q=0.5)

  cvt_x_f<<<26624, 256, 0, stream>>>(x, xpad, mL0, d00, d01);
  cvt_w_f<<<7810, 256, 0, stream>>>(W[0],W[1],W[2],W[3],W[4],W[5],W[6], WT1, WT);

  dim3 g(1024), b(512);
  // masks: mL0 by cvt_x (used g2); mL1 by g1 (used g4); mL2 by g2+g3 (used g6)
  // coverage: 1024 blk x 8 waves = 8192 waves; x64 = 524288, x32 = 262144
  gemm_r<false><<<g, b, 0, stream>>>(xpad, WT1,           B[0], nullptr, 1.0f,      hA, 832,
                                     mL1, 0u,       64, 3, d10, d11, 0.7f);
  gemm_r<true ><<<g, b, 0, stream>>>(hA,   WT + 0*262144, B[1], mL0,     1.0f/0.8f, hB, 512,
                                     mL2, 0u,       32, 2, d20, d21, 0.5f);
  gemm_r<false><<<g, b, 0, stream>>>(hB,   WT + 1*262144, B[2], nullptr, 1.0f,      hA, 512,
                                     mL2, 262144u,  32, 2, d20, d21, 0.5f);
  gemm_r<true ><<<g, b, 0, stream>>>(hA,   WT + 2*262144, B[3], mL1,     1.0f/0.7f, hB, 512,
                                     nullptr, 0u, 0, 0, 0u, 0u, 0.f);
  gemm_r<false><<<g, b, 0, stream>>>(hB,   WT + 3*262144, B[4], nullptr, 1.0f,      hA, 512,
                                     nullptr, 0u, 0, 0, 0u, 0u, 0.f);
  gemm_r<true ><<<g, b, 0, stream>>>(hA,   WT + 4*262144, B[5], mL2,     2.0f,      hB, 512,
                                     nullptr, 0u, 0, 0, 0u, 0u, 0.f);
  gemm_r<false><<<g, b, 0, stream>>>(hB,   WT + 5*262144, B[6], nullptr, 1.0f,      hA, 512,
                                     nullptr, 0u, 0, 0, 0u, 0u, 0.f);
  head_f<<<16384, 256, 0, stream>>>(hA, W[7], B[7], (float*)d_out);
}